// Round 4
// baseline (1917.154 us; speedup 1.0000x reference)
//
#include <hip/hip_runtime.h>
#include <hip/hip_bf16.h>

#define NN 100000
#define NE 1600000
#define FIN 500
#define HID 128

__device__ __forceinline__ float bf2f(unsigned short u) {
    return __uint_as_float(((unsigned int)u) << 16);
}

// ---------- template-named kernel (serves as cnt zeroing) ----------

__global__ __launch_bounds__(256) void GCNLarge_20761871909627_kernel(int* __restrict__ buf, int n) {
    int i = blockIdx.x * 256 + threadIdx.x;
    if (i < n) buf[i] = 0;
}

// ---------- runtime layout detection ----------
// flags[0]: edge_index storage is int64 (1) vs int32 (0)
// flags[1]: float tensors are bf16 (1) vs float32 (0)

__global__ void detect_kernel(const int* __restrict__ ei, const unsigned int* __restrict__ xw,
                              int* __restrict__ flags) {
    if (threadIdx.x == 0 && blockIdx.x == 0) {
        int any = 0;
        for (int k = 1; k < 257; k += 2) any |= ei[k];     // int64 => high words all zero
        flags[0] = (any == 0) ? 1 : 0;
        int hits = 0;
        for (int k = 0; k < 256; k++) {
            unsigned e = (xw[k] >> 7) & 0xFF;              // exponent of LOW u16 viewed as bf16
            hits += (e >= 100 && e <= 140) ? 1 : 0;        // bf16 N(0,1) => ~always; f32 mantissa => ~16%
        }
        flags[1] = (hits >= 128) ? 1 : 0;
    }
}

__device__ __forceinline__ int edge_src(const int* ei, int e, int m) {
    return m ? ei[2 * (size_t)e] : ei[e];
}
__device__ __forceinline__ int edge_dst(const int* ei, int e, int m) {
    return m ? ei[2 * (size_t)NE + 2 * (size_t)e] : ei[(size_t)NE + e];
}

// ---------- degree / CSR build ----------

__global__ __launch_bounds__(256) void count_kernel(const int* __restrict__ ei,
                                                    const int* __restrict__ flags,
                                                    int* __restrict__ cnt) {
    int e = blockIdx.x * 256 + threadIdx.x;
    if (e < NE) {
        int d = edge_dst(ei, e, flags[0]);
        if ((unsigned)d < NN) atomicAdd(&cnt[d], 1);
    }
}

__global__ __launch_bounds__(256) void dis_kernel(const int* __restrict__ cnt,
                                                  float* __restrict__ dis) {
    int i = blockIdx.x * 256 + threadIdx.x;
    if (i < NN) {
        int c = cnt[i];
        if (c < 0) c = 0;
        dis[i] = rsqrtf((float)(c + 1));   // +1 self-loop; always > 0
    }
}

__global__ __launch_bounds__(1024) void scan1_kernel(const int* __restrict__ cnt,
                                                     int* __restrict__ off,
                                                     int* __restrict__ bsum) {
    __shared__ int s[1024];
    int i = blockIdx.x * 1024 + threadIdx.x;
    int v = (i < NN) ? cnt[i] : 0;
    s[threadIdx.x] = v;
    __syncthreads();
    for (int d = 1; d < 1024; d <<= 1) {
        int tv = (threadIdx.x >= d) ? s[threadIdx.x - d] : 0;
        __syncthreads();
        s[threadIdx.x] += tv;
        __syncthreads();
    }
    if (i < NN) off[i] = s[threadIdx.x] - v;
    if (threadIdx.x == 1023) bsum[blockIdx.x] = s[1023];
}

__global__ void scan2_kernel(int* __restrict__ bsum, int nb) {
    if (threadIdx.x == 0 && blockIdx.x == 0) {
        int acc = 0;
        for (int b = 0; b < nb; b++) { int v = bsum[b]; bsum[b] = acc; acc += v; }
    }
}

__global__ __launch_bounds__(1024) void scan3_kernel(int* __restrict__ off,
                                                     const int* __restrict__ bsum,
                                                     int* __restrict__ cursor) {
    int i = blockIdx.x * 1024 + threadIdx.x;
    if (i < NN) { int o = off[i] + bsum[blockIdx.x]; off[i] = o; cursor[i] = o; }
    if (i == 0) off[NN] = NE;
}

__global__ __launch_bounds__(256) void place_kernel(const int* __restrict__ ei,
                                                    const int* __restrict__ flags,
                                                    int* __restrict__ cursor,
                                                    int* __restrict__ csr) {
    int e = blockIdx.x * 256 + threadIdx.x;
    if (e < NE) {
        int m = flags[0];
        int s = edge_src(ei, e, m);
        int d = edge_dst(ei, e, m);
        if ((unsigned)s < NN && (unsigned)d < NN) {
            int slot = atomicAdd(&cursor[d], 1);
            if ((unsigned)slot < NE) csr[slot] = s;
        }
    }
}

// ---------- dual-dtype float4 load ----------

__device__ __forceinline__ float4 load4(const void* p, size_t elem_off, int bf) {
    if (bf) {
        ushort4 a = *(const ushort4*)((const unsigned short*)p + elem_off);
        return make_float4(bf2f(a.x), bf2f(a.y), bf2f(a.z), bf2f(a.w));
    }
    return *(const float4*)((const float*)p + elem_off);
}

// ---------- GEMM layer 1: x [NN,500] @ W1 [500,128] -> f32, row-scaled by dis ----------

__global__ __launch_bounds__(256) void gemm1_kernel(const void* __restrict__ Av,
                                                    const void* __restrict__ Wv,
                                                    const float* __restrict__ dis,
                                                    const int* __restrict__ flags,
                                                    float* __restrict__ out) {
    __shared__ float Wsf[50 * 128];
    __shared__ float As[32][108];     // stride 108: 2-way (free) bank aliasing
    int tid = threadIdx.x;
    int bf = flags[1];
    int c8 = (tid & 15) * 8;          // 8 output cols
    int rg = tid >> 4;                // rows rg and rg+16
    int r0 = blockIdx.x * 32;
    float acc0[8], acc1[8];
#pragma unroll
    for (int j = 0; j < 8; j++) { acc0[j] = 0.f; acc1[j] = 0.f; }
    for (int kt = 0; kt < 5; kt++) {
        int kb = kt * 100;
        for (int idx = tid; idx < 800; idx += 256) {   // 32 rows x 25 quads
            int rr = idx / 25;
            int kk = (idx - rr * 25) * 4;
            float4 af = load4(Av, (size_t)(r0 + rr) * FIN + kb + kk, bf);
            *(float4*)&As[rr][kk] = af;
        }
        for (int h = 0; h < 2; h++) {
            for (int idx = tid; idx < 1600; idx += 256) {  // 50 rows x 32 quads
                int r = idx >> 5;
                int c = (idx & 31) * 4;
                float4 wf = load4(Wv, (size_t)(kb + 50 * h + r) * HID + c, bf);
                *(float4*)&Wsf[r * 128 + c] = wf;
            }
            __syncthreads();
            int k0 = 50 * h;
#pragma unroll 2
            for (int k = 0; k < 50; k++) {
                float a0 = As[rg][k0 + k], a1 = As[rg + 16][k0 + k];
                const float* wr = &Wsf[k * 128 + c8];
#pragma unroll
                for (int j = 0; j < 8; j++) {
                    float wf = wr[j];
                    acc0[j] += a0 * wf;
                    acc1[j] += a1 * wf;
                }
            }
            __syncthreads();
        }
    }
    int row0 = r0 + rg, row1 = r0 + rg + 16;
    float d0 = dis[row0], d1 = dis[row1];
    *(float4*)&out[(size_t)row0 * HID + c8]     = make_float4(acc0[0]*d0, acc0[1]*d0, acc0[2]*d0, acc0[3]*d0);
    *(float4*)&out[(size_t)row0 * HID + c8 + 4] = make_float4(acc0[4]*d0, acc0[5]*d0, acc0[6]*d0, acc0[7]*d0);
    *(float4*)&out[(size_t)row1 * HID + c8]     = make_float4(acc1[0]*d1, acc1[1]*d1, acc1[2]*d1, acc1[3]*d1);
    *(float4*)&out[(size_t)row1 * HID + c8 + 4] = make_float4(acc1[4]*d1, acc1[5]*d1, acc1[6]*d1, acc1[7]*d1);
}

// ---------- GEMM layers 2-4: f32 [NN,128] @ W [128,128] -> f32, row-scaled by dis ----------

__global__ __launch_bounds__(256) void gemm128_kernel(const float* __restrict__ A,
                                                      const void* __restrict__ Wv,
                                                      const float* __restrict__ dis,
                                                      const int* __restrict__ flags,
                                                      float* __restrict__ out) {
    __shared__ float Wsf[64 * 128];
    __shared__ float As[32][132];
    int tid = threadIdx.x;
    int bf = flags[1];
    int c8 = (tid & 15) * 8;
    int rg = tid >> 4;                // rows rg, rg+16
    int r0 = blockIdx.x * 32;
    for (int idx = tid; idx < 1024; idx += 256) {   // 32 rows x 32 quads
        int rr = idx >> 5;
        int kk = (idx & 31) * 4;
        *(float4*)&As[rr][kk] = *(const float4*)(A + (size_t)r0 * HID + idx * 4);
    }
    float acc0[8], acc1[8];
#pragma unroll
    for (int j = 0; j < 8; j++) { acc0[j] = 0.f; acc1[j] = 0.f; }
    for (int s = 0; s < 2; s++) {
        for (int idx = tid; idx < 2048; idx += 256) {  // 64 rows x 32 quads
            int r = idx >> 5;
            int c = (idx & 31) * 4;
            float4 wf = load4(Wv, (size_t)(64 * s + r) * HID + c, bf);
            *(float4*)&Wsf[r * 128 + c] = wf;
        }
        __syncthreads();
        int k0 = 64 * s;
#pragma unroll 2
        for (int k = 0; k < 64; k++) {
            float a0 = As[rg][k0 + k], a1 = As[rg + 16][k0 + k];
            const float* wr = &Wsf[k * 128 + c8];
#pragma unroll
            for (int j = 0; j < 8; j++) {
                float wf = wr[j];
                acc0[j] += a0 * wf;
                acc1[j] += a1 * wf;
            }
        }
        __syncthreads();
    }
    int row0 = r0 + rg, row1 = r0 + rg + 16;
    float d0 = dis[row0], d1 = dis[row1];
    *(float4*)&out[(size_t)row0 * HID + c8]     = make_float4(acc0[0]*d0, acc0[1]*d0, acc0[2]*d0, acc0[3]*d0);
    *(float4*)&out[(size_t)row0 * HID + c8 + 4] = make_float4(acc0[4]*d0, acc0[5]*d0, acc0[6]*d0, acc0[7]*d0);
    *(float4*)&out[(size_t)row1 * HID + c8]     = make_float4(acc1[0]*d1, acc1[1]*d1, acc1[2]*d1, acc1[3]*d1);
    *(float4*)&out[(size_t)row1 * HID + c8 + 4] = make_float4(acc1[4]*d1, acc1[5]*d1, acc1[6]*d1, acc1[7]*d1);
}

// ---------- aggregation ----------
// scale_src=0 (tin pre-scaled by dis[row]): out[i] = dis[i]*(t[i] + sum t[src]) + b
// scale_src=1 (tin unscaled):               out[i] = dis[i]*(dis[i]*t[i] + sum dis[src]*t[src])

__global__ __launch_bounds__(256) void agg_kernel(const float* __restrict__ tin,
                                                  const int* __restrict__ off,
                                                  const int* __restrict__ csr,
                                                  const float* __restrict__ dis,
                                                  const void* __restrict__ bias,
                                                  const int* __restrict__ flags,
                                                  float* __restrict__ hout,
                                                  int relu, int scale_src) {
    int node = blockIdx.x * 4 + (threadIdx.x >> 6);  // one wave per node
    int lane = threadIdx.x & 63;                     // 2 features per lane
    float di = dis[node];
    float2 self = *(const float2*)(tin + (size_t)node * HID + lane * 2);
    float acc0 = scale_src ? di * self.x : self.x;
    float acc1 = scale_src ? di * self.y : self.y;
    int e0 = off[node], e1 = off[node + 1];
    if (e0 < 0) e0 = 0;
    if (e1 > NE) e1 = NE;
    if (scale_src) {
        for (int e = e0; e < e1; e++) {
            unsigned s = (unsigned)csr[e];
            if (s >= NN) continue;
            float2 v = *(const float2*)(tin + (size_t)s * HID + lane * 2);
            float m = dis[s];
            acc0 += m * v.x; acc1 += m * v.y;
        }
    } else {
        for (int e = e0; e < e1; e++) {
            unsigned s = (unsigned)csr[e];
            if (s >= NN) continue;
            float2 v = *(const float2*)(tin + (size_t)s * HID + lane * 2);
            acc0 += v.x; acc1 += v.y;
        }
    }
    float o0 = di * acc0, o1 = di * acc1;
    if (bias) {
        if (flags[1]) { o0 += bf2f(((const unsigned short*)bias)[lane * 2]);
                        o1 += bf2f(((const unsigned short*)bias)[lane * 2 + 1]); }
        else          { o0 += ((const float*)bias)[lane * 2];
                        o1 += ((const float*)bias)[lane * 2 + 1]; }
    }
    if (relu) { o0 = fmaxf(o0, 0.f); o1 = fmaxf(o1, 0.f); }
    *(float2*)(hout + (size_t)node * HID + lane * 2) = make_float2(o0, o1);
}

// ---------- layer 5 GEMM: f32 [NN,128] @ W5 [128,3] + b5 -> out (dtype per flags[1]) ----------

__global__ __launch_bounds__(256) void gemm5_kernel(const float* __restrict__ A,
                                                    const void* __restrict__ W5v,
                                                    const void* __restrict__ b5v,
                                                    const int* __restrict__ flags,
                                                    void* __restrict__ outv) {
    __shared__ float Ws[384];
    __shared__ float bs[3];
    int tid = threadIdx.x;
    int bf = flags[1];
    for (int idx = tid; idx < 384; idx += 256)
        Ws[idx] = bf ? bf2f(((const unsigned short*)W5v)[idx]) : ((const float*)W5v)[idx];
    if (tid < 3)
        bs[tid] = bf ? bf2f(((const unsigned short*)b5v)[tid]) : ((const float*)b5v)[tid];
    __syncthreads();
    int lane = tid & 63;
    int row = blockIdx.x * 4 + (tid >> 6);  // one wave per row
    float a0 = A[(size_t)row * HID + lane];
    float a1 = A[(size_t)row * HID + 64 + lane];
    float c0 = a0 * Ws[lane * 3 + 0] + a1 * Ws[(lane + 64) * 3 + 0];
    float c1 = a0 * Ws[lane * 3 + 1] + a1 * Ws[(lane + 64) * 3 + 1];
    float c2 = a0 * Ws[lane * 3 + 2] + a1 * Ws[(lane + 64) * 3 + 2];
#pragma unroll
    for (int o = 32; o > 0; o >>= 1) {
        c0 += __shfl_down(c0, o);
        c1 += __shfl_down(c1, o);
        c2 += __shfl_down(c2, o);
    }
    if (lane == 0) {
        c0 += bs[0]; c1 += bs[1]; c2 += bs[2];
        if (bf) {
            unsigned short* out = (unsigned short*)outv;
            __hip_bfloat16 h0 = __float2bfloat16(c0);
            __hip_bfloat16 h1 = __float2bfloat16(c1);
            __hip_bfloat16 h2 = __float2bfloat16(c2);
            out[(size_t)row * 3 + 0] = *(unsigned short*)&h0;
            out[(size_t)row * 3 + 1] = *(unsigned short*)&h1;
            out[(size_t)row * 3 + 2] = *(unsigned short*)&h2;
        } else {
            float* out = (float*)outv;
            out[(size_t)row * 3 + 0] = c0;
            out[(size_t)row * 3 + 1] = c1;
            out[(size_t)row * 3 + 2] = c2;
        }
    }
}

extern "C" void kernel_launch(void* const* d_in, const int* in_sizes, int n_in,
                              void* d_out, int out_size, void* d_ws, size_t ws_size,
                              hipStream_t stream) {
    // Resolve inputs BY SIZE — robust to input ordering.
    const void* x = nullptr; const int* ei = nullptr;
    const void* W1 = nullptr; const void* W5 = nullptr; const void* b5 = nullptr;
    const void* Wmid[3] = {nullptr, nullptr, nullptr};
    const void* bvec[4] = {nullptr, nullptr, nullptr, nullptr};
    int nw = 0, nb = 0;
    for (int i = 0; i < n_in; i++) {
        int s = in_sizes[i];
        if      (s == 50000000) x = d_in[i];
        else if (s == 3200000)  ei = (const int*)d_in[i];
        else if (s == 64000)    W1 = d_in[i];
        else if (s == 16384)  { if (nw < 3) Wmid[nw++] = d_in[i]; }
        else if (s == 384)      W5 = d_in[i];
        else if (s == 128)    { if (nb < 4) bvec[nb++] = d_in[i]; }
        else if (s == 3)        b5 = d_in[i];
    }
    if (!x || !ei || !W1 || !W5 || !b5 || nw < 3 || nb < 4) return;

    char* p = (char*)d_ws;
    auto alloc = [&](size_t bytes) { char* q = p; p += (bytes + 255) & ~(size_t)255; return (void*)q; };
    int*   flags = (int*)alloc(256);
    float* dis   = (float*)alloc((size_t)NN * 4);
    int*   cnt   = (int*)alloc((size_t)NN * 4);
    int*   off   = (int*)alloc((size_t)(NN + 1) * 4);
    int*   cur   = (int*)alloc((size_t)NN * 4);
    int*   bsum  = (int*)alloc(128 * 4);
    int*   csr   = (int*)alloc((size_t)NE * 4);
    float* T     = (float*)alloc((size_t)NN * HID * 4);  // gemm outputs
    float* H     = (float*)alloc((size_t)NN * HID * 4);  // activations

    // graph build
    GCNLarge_20761871909627_kernel<<<(NN + 255) / 256, 256, 0, stream>>>(cnt, NN);
    detect_kernel<<<1, 64, 0, stream>>>(ei, (const unsigned int*)x, flags);
    count_kernel<<<(NE + 255) / 256, 256, 0, stream>>>(ei, flags, cnt);
    dis_kernel<<<(NN + 255) / 256, 256, 0, stream>>>(cnt, dis);
    scan1_kernel<<<98, 1024, 0, stream>>>(cnt, off, bsum);
    scan2_kernel<<<1, 64, 0, stream>>>(bsum, 98);
    scan3_kernel<<<98, 1024, 0, stream>>>(off, bsum, cur);
    place_kernel<<<(NE + 255) / 256, 256, 0, stream>>>(ei, flags, cur, csr);

    // layer 1
    gemm1_kernel<<<NN / 32, 256, 0, stream>>>(x, W1, dis, flags, T);
    agg_kernel<<<NN / 4, 256, 0, stream>>>(T, off, csr, dis, bvec[0], flags, H, 1, 0);
    // layers 2-4: strict T/H ping-pong, no aliasing
    gemm128_kernel<<<NN / 32, 256, 0, stream>>>(H, Wmid[0], dis, flags, T);
    agg_kernel<<<NN / 4, 256, 0, stream>>>(T, off, csr, dis, bvec[1], flags, H, 1, 0);
    gemm128_kernel<<<NN / 32, 256, 0, stream>>>(H, Wmid[1], dis, flags, T);
    agg_kernel<<<NN / 4, 256, 0, stream>>>(T, off, csr, dis, bvec[2], flags, H, 1, 0);
    gemm128_kernel<<<NN / 32, 256, 0, stream>>>(H, Wmid[2], dis, flags, T);
    agg_kernel<<<NN / 4, 256, 0, stream>>>(T, off, csr, dis, bvec[3], flags, H, 1, 0);
    // layer 5: aggregate first (linearity), then small GEMM; output dtype per flags[1]
    agg_kernel<<<NN / 4, 256, 0, stream>>>(H, off, csr, dis, nullptr, flags, T, 0, 1);
    gemm5_kernel<<<NN / 4, 256, 0, stream>>>(T, W5, b5, flags, d_out);
}

// Round 5
// 1479.102 us; speedup vs baseline: 1.2962x; 1.2962x over previous
//
#include <hip/hip_runtime.h>
#include <hip/hip_bf16.h>

#define NN 100000
#define NNP 100096   // padded rows: multiple of 64
#define NE 1600000
#define FIN 500
#define HID 128
#define LDK 136      // LDS k-stride in bf16 elems: rows 16B-aligned, <=2-way bank aliasing

typedef __attribute__((ext_vector_type(8))) short short8;   // 8 bf16 = 4 VGPRs (MFMA A/B frag)
typedef __attribute__((ext_vector_type(4))) float f32x4;    // MFMA C/D frag

__device__ __forceinline__ float bf2f(unsigned short u) {
    return __uint_as_float(((unsigned int)u) << 16);
}
__device__ __forceinline__ unsigned short f2bf(float f) {
    __hip_bfloat16 h = __float2bfloat16(f);
    return *(unsigned short*)&h;
}

// ---------- template-named kernel (serves as cnt zeroing) ----------

__global__ __launch_bounds__(256) void GCNLarge_20761871909627_kernel(int* __restrict__ buf, int n) {
    int i = blockIdx.x * 256 + threadIdx.x;
    if (i < n) buf[i] = 0;
}

// ---------- runtime layout detection ----------
// flags[0]: edge_index int64 (1) vs int32 (0);  flags[1]: floats bf16 (1) vs f32 (0)

__global__ void detect_kernel(const int* __restrict__ ei, const unsigned int* __restrict__ xw,
                              int* __restrict__ flags) {
    if (threadIdx.x == 0 && blockIdx.x == 0) {
        int any = 0;
        for (int k = 1; k < 257; k += 2) any |= ei[k];
        flags[0] = (any == 0) ? 1 : 0;
        int hits = 0;
        for (int k = 0; k < 256; k++) {
            unsigned e = (xw[k] >> 7) & 0xFF;
            hits += (e >= 100 && e <= 140) ? 1 : 0;
        }
        flags[1] = (hits >= 128) ? 1 : 0;
    }
}

__device__ __forceinline__ int edge_src(const int* ei, int e, int m) {
    return m ? ei[2 * (size_t)e] : ei[e];
}
__device__ __forceinline__ int edge_dst(const int* ei, int e, int m) {
    return m ? ei[2 * (size_t)NE + 2 * (size_t)e] : ei[(size_t)NE + e];
}

// ---------- degree / CSR build ----------

__global__ __launch_bounds__(256) void count_kernel(const int* __restrict__ ei,
                                                    const int* __restrict__ flags,
                                                    int* __restrict__ cnt) {
    int e = blockIdx.x * 256 + threadIdx.x;
    if (e < NE) {
        int d = edge_dst(ei, e, flags[0]);
        if ((unsigned)d < NN) atomicAdd(&cnt[d], 1);
    }
}

__global__ __launch_bounds__(256) void dis_kernel(const int* __restrict__ cnt,
                                                  float* __restrict__ dis) {
    int i = blockIdx.x * 256 + threadIdx.x;
    if (i < NNP) {
        int c = (i < NN) ? cnt[i] : 0;
        if (c < 0) c = 0;
        dis[i] = rsqrtf((float)(c + 1));
    }
}

__global__ __launch_bounds__(1024) void scan1_kernel(const int* __restrict__ cnt,
                                                     int* __restrict__ off,
                                                     int* __restrict__ bsum) {
    __shared__ int s[1024];
    int i = blockIdx.x * 1024 + threadIdx.x;
    int v = (i < NN) ? cnt[i] : 0;
    s[threadIdx.x] = v;
    __syncthreads();
    for (int d = 1; d < 1024; d <<= 1) {
        int tv = (threadIdx.x >= d) ? s[threadIdx.x - d] : 0;
        __syncthreads();
        s[threadIdx.x] += tv;
        __syncthreads();
    }
    if (i < NN) off[i] = s[threadIdx.x] - v;
    if (threadIdx.x == 1023) bsum[blockIdx.x] = s[1023];
}

__global__ void scan2_kernel(int* __restrict__ bsum, int nb) {
    if (threadIdx.x == 0 && blockIdx.x == 0) {
        int acc = 0;
        for (int b = 0; b < nb; b++) { int v = bsum[b]; bsum[b] = acc; acc += v; }
    }
}

__global__ __launch_bounds__(1024) void scan3_kernel(int* __restrict__ off,
                                                     const int* __restrict__ bsum,
                                                     int* __restrict__ cursor) {
    int i = blockIdx.x * 1024 + threadIdx.x;
    if (i < NN) { int o = off[i] + bsum[blockIdx.x]; off[i] = o; cursor[i] = o; }
    if (i == 0) off[NN] = NE;
}

__global__ __launch_bounds__(256) void place_kernel(const int* __restrict__ ei,
                                                    const int* __restrict__ flags,
                                                    int* __restrict__ cursor,
                                                    int* __restrict__ csr) {
    int e = blockIdx.x * 256 + threadIdx.x;
    if (e < NE) {
        int m = flags[0];
        int s = edge_src(ei, e, m);
        int d = edge_dst(ei, e, m);
        if ((unsigned)s < NN && (unsigned)d < NN) {
            int slot = atomicAdd(&cursor[d], 1);
            if ((unsigned)slot < NE) csr[slot] = s;
        }
    }
}

// ---------- W -> W^T (bf16) in global: Wt[n][k] = W[k][n], zero-padded to Kpad ----------

__global__ __launch_bounds__(256) void wt_kernel(const void* __restrict__ W,
                                                 const int* __restrict__ flags,
                                                 unsigned short* __restrict__ Wt,
                                                 int K, int Kpad, int total) {
    int idx = blockIdx.x * 256 + threadIdx.x;
    if (idx >= total) return;
    int n = idx / Kpad, k = idx - n * Kpad;
    unsigned short v = 0;
    if (k < K) {
        if (flags[1]) v = ((const unsigned short*)W)[(size_t)k * HID + n];
        else          v = f2bf(((const float*)W)[(size_t)k * HID + n]);
    }
    Wt[idx] = v;
}

// ---------- MFMA GEMM, layers 2-4: bf16 [NNP,128] @ (Wt bf16 [128][128]) -> bf16, row-scaled ----------
// Block: 256 thr (4 waves), tile 64 rows x 128 cols; wave = 2 m-tiles x 4 n-tiles of 16x16.

__global__ __launch_bounds__(256) void gemm128m_kernel(const unsigned short* __restrict__ A,
                                                       const unsigned short* __restrict__ Wt,
                                                       const float* __restrict__ dis,
                                                       unsigned short* __restrict__ out) {
    __shared__ unsigned short As[64 * LDK];
    __shared__ unsigned short Bs[128 * LDK];
    int tid = threadIdx.x;
    int r0 = blockIdx.x * 64;
    for (int idx = tid; idx < 1024; idx += 256) {      // A: 64 rows x 16 x (8 bf16)
        int r = idx >> 4, q = idx & 15;
        *(short8*)&As[r * LDK + q * 8] = *(const short8*)(A + (size_t)(r0 + r) * HID + q * 8);
    }
    for (int idx = tid; idx < 2048; idx += 256) {      // Wt: 128 rows x 16 x (8 bf16)
        int n = idx >> 4, q = idx & 15;
        *(short8*)&Bs[n * LDK + q * 8] = *(const short8*)(Wt + (size_t)n * HID + q * 8);
    }
    __syncthreads();
    int w = tid >> 6, lane = tid & 63;
    int m = lane & 15, quad = lane >> 4;
    int mbase = (w >> 1) * 32, nbase = (w & 1) * 64;
    f32x4 acc[2][4] = {};
#pragma unroll
    for (int kq = 0; kq < 4; kq++) {
        short8 a0 = *(const short8*)&As[(mbase + m) * LDK + kq * 32 + quad * 8];
        short8 a1 = *(const short8*)&As[(mbase + 16 + m) * LDK + kq * 32 + quad * 8];
#pragma unroll
        for (int nt = 0; nt < 4; nt++) {
            short8 b = *(const short8*)&Bs[(nbase + nt * 16 + m) * LDK + kq * 32 + quad * 8];
            acc[0][nt] = __builtin_amdgcn_mfma_f32_16x16x32_bf16(a0, b, acc[0][nt], 0, 0, 0);
            acc[1][nt] = __builtin_amdgcn_mfma_f32_16x16x32_bf16(a1, b, acc[1][nt], 0, 0, 0);
        }
    }
#pragma unroll
    for (int mt = 0; mt < 2; mt++) {
        int rb = r0 + mbase + mt * 16 + quad * 4;      // C/D: row = quad*4+reg, col = lane&15
#pragma unroll
        for (int reg = 0; reg < 4; reg++) {
            float d = dis[rb + reg];
#pragma unroll
            for (int nt = 0; nt < 4; nt++)
                out[(size_t)(rb + reg) * HID + nbase + nt * 16 + m] = f2bf(acc[mt][nt][reg] * d);
        }
    }
}

// ---------- MFMA GEMM, layer 1: x [NN,500] @ (Wt1 bf16 [128][512]) -> bf16, row-scaled ----------

__global__ __launch_bounds__(256) void gemm1m_kernel(const void* __restrict__ Av,
                                                     const unsigned short* __restrict__ Wt1,
                                                     const float* __restrict__ dis,
                                                     const int* __restrict__ flags,
                                                     unsigned short* __restrict__ out) {
    __shared__ unsigned short As[64 * LDK];
    __shared__ unsigned short Bs[128 * LDK];
    int tid = threadIdx.x;
    int r0 = blockIdx.x * 64;
    int bf = flags[1];
    int w = tid >> 6, lane = tid & 63;
    int m = lane & 15, quad = lane >> 4;
    int mbase = (w >> 1) * 32, nbase = (w & 1) * 64;
    f32x4 acc[2][4] = {};
    for (int kc = 0; kc < 4; kc++) {
        int k0 = kc * 128;
        __syncthreads();
        for (int idx = tid; idx < 2048; idx += 256) {  // A chunk: 64 rows x 32 x (4 bf16)
            int r = idx >> 5, q = idx & 31;
            int grow = r0 + r; if (grow >= NN) grow = NN - 1;
            int kk = k0 + q * 4;
            ushort4 val;
            if (kk + 4 <= FIN) {
                if (bf) val = *(const ushort4*)((const unsigned short*)Av + (size_t)grow * FIN + kk);
                else {
                    const float* fp = (const float*)Av + (size_t)grow * FIN + kk;
                    val = make_ushort4(f2bf(fp[0]), f2bf(fp[1]), f2bf(fp[2]), f2bf(fp[3]));
                }
            } else val = make_ushort4(0, 0, 0, 0);
            *(ushort4*)&As[r * LDK + q * 4] = val;
        }
        for (int idx = tid; idx < 2048; idx += 256) {  // Wt chunk: 128 rows x 16 x (8 bf16)
            int n = idx >> 4, q = idx & 15;
            *(short8*)&Bs[n * LDK + q * 8] = *(const short8*)(Wt1 + (size_t)n * 512 + k0 + q * 8);
        }
        __syncthreads();
#pragma unroll
        for (int kq = 0; kq < 4; kq++) {
            short8 a0 = *(const short8*)&As[(mbase + m) * LDK + kq * 32 + quad * 8];
            short8 a1 = *(const short8*)&As[(mbase + 16 + m) * LDK + kq * 32 + quad * 8];
#pragma unroll
            for (int nt = 0; nt < 4; nt++) {
                short8 b = *(const short8*)&Bs[(nbase + nt * 16 + m) * LDK + kq * 32 + quad * 8];
                acc[0][nt] = __builtin_amdgcn_mfma_f32_16x16x32_bf16(a0, b, acc[0][nt], 0, 0, 0);
                acc[1][nt] = __builtin_amdgcn_mfma_f32_16x16x32_bf16(a1, b, acc[1][nt], 0, 0, 0);
            }
        }
    }
#pragma unroll
    for (int mt = 0; mt < 2; mt++) {
        int rb = r0 + mbase + mt * 16 + quad * 4;
#pragma unroll
        for (int reg = 0; reg < 4; reg++) {
            int row = rb + reg;
            if (row < NN) {
                float d = dis[row];
#pragma unroll
                for (int nt = 0; nt < 4; nt++)
                    out[(size_t)row * HID + nbase + nt * 16 + m] = f2bf(acc[mt][nt][reg] * d);
            }
        }
    }
}

// ---------- aggregation over bf16 features, f32 accumulate ----------
// scale_src=0 (tin pre-scaled by dis[row]): out[i] = relu(dis[i]*(t[i] + sum t[src]) + b)
// scale_src=1 (tin unscaled):               out[i] = dis[i]*(dis[i]*t[i] + sum dis[src]*t[src])

__global__ __launch_bounds__(256) void aggb_kernel(const unsigned short* __restrict__ tin,
                                                   const int* __restrict__ off,
                                                   const int* __restrict__ csr,
                                                   const float* __restrict__ dis,
                                                   const void* __restrict__ bias,
                                                   const int* __restrict__ flags,
                                                   unsigned short* __restrict__ hout,
                                                   int relu, int scale_src) {
    int node = blockIdx.x * 4 + (threadIdx.x >> 6);   // one wave per node
    int lane = threadIdx.x & 63;                      // 2 features per lane (1 dword)
    float di = dis[node];
    unsigned int sv = *(const unsigned int*)(tin + (size_t)node * HID + lane * 2);
    float s0 = __uint_as_float(sv << 16);
    float s1 = __uint_as_float(sv & 0xffff0000u);
    float acc0 = scale_src ? di * s0 : s0;
    float acc1 = scale_src ? di * s1 : s1;
    int e0 = off[node], e1 = off[node + 1];
    if (e0 < 0) e0 = 0;
    if (e1 > NE) e1 = NE;
    if (scale_src) {
        for (int e = e0; e < e1; e++) {
            unsigned s = (unsigned)csr[e];
            if (s >= NN) continue;
            unsigned int v = *(const unsigned int*)(tin + (size_t)s * HID + lane * 2);
            float mm = dis[s];
            acc0 += mm * __uint_as_float(v << 16);
            acc1 += mm * __uint_as_float(v & 0xffff0000u);
        }
    } else {
        for (int e = e0; e < e1; e++) {
            unsigned s = (unsigned)csr[e];
            if (s >= NN) continue;
            unsigned int v = *(const unsigned int*)(tin + (size_t)s * HID + lane * 2);
            acc0 += __uint_as_float(v << 16);
            acc1 += __uint_as_float(v & 0xffff0000u);
        }
    }
    float o0 = di * acc0, o1 = di * acc1;
    if (bias) {
        if (flags[1]) { o0 += bf2f(((const unsigned short*)bias)[lane * 2]);
                        o1 += bf2f(((const unsigned short*)bias)[lane * 2 + 1]); }
        else          { o0 += ((const float*)bias)[lane * 2];
                        o1 += ((const float*)bias)[lane * 2 + 1]; }
    }
    if (relu) { o0 = fmaxf(o0, 0.f); o1 = fmaxf(o1, 0.f); }
    unsigned int pk = ((unsigned int)f2bf(o1) << 16) | (unsigned int)f2bf(o0);
    *(unsigned int*)(hout + (size_t)node * HID + lane * 2) = pk;
}

// ---------- layer 5: bf16 [NN,128] @ W5 [128,3] + b5 -> out (dtype per flags[1]) ----------

__global__ __launch_bounds__(256) void gemm5_kernel(const unsigned short* __restrict__ A,
                                                    const void* __restrict__ W5v,
                                                    const void* __restrict__ b5v,
                                                    const int* __restrict__ flags,
                                                    void* __restrict__ outv) {
    __shared__ float Ws[384];
    __shared__ float bs[3];
    int tid = threadIdx.x;
    int bf = flags[1];
    for (int idx = tid; idx < 384; idx += 256)
        Ws[idx] = bf ? bf2f(((const unsigned short*)W5v)[idx]) : ((const float*)W5v)[idx];
    if (tid < 3)
        bs[tid] = bf ? bf2f(((const unsigned short*)b5v)[tid]) : ((const float*)b5v)[tid];
    __syncthreads();
    int lane = tid & 63;
    int row = blockIdx.x * 4 + (tid >> 6);
    float a0 = bf2f(A[(size_t)row * HID + lane]);
    float a1 = bf2f(A[(size_t)row * HID + 64 + lane]);
    float c0 = a0 * Ws[lane * 3 + 0] + a1 * Ws[(lane + 64) * 3 + 0];
    float c1 = a0 * Ws[lane * 3 + 1] + a1 * Ws[(lane + 64) * 3 + 1];
    float c2 = a0 * Ws[lane * 3 + 2] + a1 * Ws[(lane + 64) * 3 + 2];
#pragma unroll
    for (int o = 32; o > 0; o >>= 1) {
        c0 += __shfl_down(c0, o);
        c1 += __shfl_down(c1, o);
        c2 += __shfl_down(c2, o);
    }
    if (lane == 0) {
        c0 += bs[0]; c1 += bs[1]; c2 += bs[2];
        if (bf) {
            unsigned short* out = (unsigned short*)outv;
            out[(size_t)row * 3 + 0] = f2bf(c0);
            out[(size_t)row * 3 + 1] = f2bf(c1);
            out[(size_t)row * 3 + 2] = f2bf(c2);
        } else {
            float* out = (float*)outv;
            out[(size_t)row * 3 + 0] = c0;
            out[(size_t)row * 3 + 1] = c1;
            out[(size_t)row * 3 + 2] = c2;
        }
    }
}

extern "C" void kernel_launch(void* const* d_in, const int* in_sizes, int n_in,
                              void* d_out, int out_size, void* d_ws, size_t ws_size,
                              hipStream_t stream) {
    // Resolve inputs BY SIZE (ordering-robust).
    const void* x = nullptr; const int* ei = nullptr;
    const void* W1 = nullptr; const void* W5 = nullptr; const void* b5 = nullptr;
    const void* Wmid[3] = {nullptr, nullptr, nullptr};
    const void* bvec[4] = {nullptr, nullptr, nullptr, nullptr};
    int nw = 0, nb = 0;
    for (int i = 0; i < n_in; i++) {
        int s = in_sizes[i];
        if      (s == 50000000) x = d_in[i];
        else if (s == 3200000)  ei = (const int*)d_in[i];
        else if (s == 64000)    W1 = d_in[i];
        else if (s == 16384)  { if (nw < 3) Wmid[nw++] = d_in[i]; }
        else if (s == 384)      W5 = d_in[i];
        else if (s == 128)    { if (nb < 4) bvec[nb++] = d_in[i]; }
        else if (s == 3)        b5 = d_in[i];
    }
    if (!x || !ei || !W1 || !W5 || !b5 || nw < 3 || nb < 4) return;

    char* p = (char*)d_ws;
    auto alloc = [&](size_t bytes) { char* q = p; p += (bytes + 255) & ~(size_t)255; return (void*)q; };
    int*   flags = (int*)alloc(256);
    float* dis   = (float*)alloc((size_t)NNP * 4);
    int*   cnt   = (int*)alloc((size_t)NN * 4);
    int*   off   = (int*)alloc((size_t)(NN + 1) * 4);
    int*   cur   = (int*)alloc((size_t)NN * 4);
    int*   bsum  = (int*)alloc(128 * 4);
    int*   csr   = (int*)alloc((size_t)NE * 4);
    unsigned short* Wt1 = (unsigned short*)alloc((size_t)128 * 512 * 2);
    unsigned short* Wt2 = (unsigned short*)alloc((size_t)128 * 128 * 2);
    unsigned short* Wt3 = (unsigned short*)alloc((size_t)128 * 128 * 2);
    unsigned short* Wt4 = (unsigned short*)alloc((size_t)128 * 128 * 2);
    unsigned short* T   = (unsigned short*)alloc((size_t)NNP * HID * 2);
    unsigned short* H   = (unsigned short*)alloc((size_t)NNP * HID * 2);

    // graph build + weight transposes
    GCNLarge_20761871909627_kernel<<<(NN + 255) / 256, 256, 0, stream>>>(cnt, NN);
    detect_kernel<<<1, 64, 0, stream>>>(ei, (const unsigned int*)x, flags);
    wt_kernel<<<256, 256, 0, stream>>>(W1, flags, Wt1, FIN, 512, 128 * 512);
    wt_kernel<<<64, 256, 0, stream>>>(Wmid[0], flags, Wt2, HID, 128, 128 * 128);
    wt_kernel<<<64, 256, 0, stream>>>(Wmid[1], flags, Wt3, HID, 128, 128 * 128);
    wt_kernel<<<64, 256, 0, stream>>>(Wmid[2], flags, Wt4, HID, 128, 128 * 128);
    count_kernel<<<(NE + 255) / 256, 256, 0, stream>>>(ei, flags, cnt);
    dis_kernel<<<(NNP + 255) / 256, 256, 0, stream>>>(cnt, dis);
    scan1_kernel<<<98, 1024, 0, stream>>>(cnt, off, bsum);
    scan2_kernel<<<1, 64, 0, stream>>>(bsum, 98);
    scan3_kernel<<<98, 1024, 0, stream>>>(off, bsum, cur);
    place_kernel<<<(NE + 255) / 256, 256, 0, stream>>>(ei, flags, cur, csr);

    const int GB = NNP / 64;  // 1564 gemm blocks
    // layer 1
    gemm1m_kernel<<<GB, 256, 0, stream>>>(x, Wt1, dis, flags, T);
    aggb_kernel<<<NN / 4, 256, 0, stream>>>(T, off, csr, dis, bvec[0], flags, H, 1, 0);
    // layers 2-4 (T/H ping-pong)
    gemm128m_kernel<<<GB, 256, 0, stream>>>(H, Wt2, dis, T);
    aggb_kernel<<<NN / 4, 256, 0, stream>>>(T, off, csr, dis, bvec[1], flags, H, 1, 0);
    gemm128m_kernel<<<GB, 256, 0, stream>>>(H, Wt3, dis, T);
    aggb_kernel<<<NN / 4, 256, 0, stream>>>(T, off, csr, dis, bvec[2], flags, H, 1, 0);
    gemm128m_kernel<<<GB, 256, 0, stream>>>(H, Wt4, dis, T);
    aggb_kernel<<<NN / 4, 256, 0, stream>>>(T, off, csr, dis, bvec[3], flags, H, 1, 0);
    // layer 5: aggregate first (linearity), then small GEMM
    aggb_kernel<<<NN / 4, 256, 0, stream>>>(H, off, csr, dis, nullptr, flags, T, 0, 1);
    gemm5_kernel<<<NN / 4, 256, 0, stream>>>(T, W5, b5, flags, d_out);
}

// Round 6
// 1013.595 us; speedup vs baseline: 1.8914x; 1.4593x over previous
//
#include <hip/hip_runtime.h>
#include <hip/hip_bf16.h>

#define NN 100000
#define NNP 100096   // padded rows: multiple of 64
#define NE 1600000
#define FIN 500
#define HID 128
#define LDK 136      // LDS k-stride in bf16 elems: rows 16B-aligned, <=2-way bank aliasing

typedef __attribute__((ext_vector_type(8))) short short8;   // 8 bf16 = 4 VGPRs (MFMA A/B frag)
typedef __attribute__((ext_vector_type(4))) float f32x4;    // MFMA C/D frag

__device__ __forceinline__ float bf2f(unsigned short u) {
    return __uint_as_float(((unsigned int)u) << 16);
}
__device__ __forceinline__ unsigned short f2bf(float f) {
    __hip_bfloat16 h = __float2bfloat16(f);
    return *(unsigned short*)&h;
}
__device__ __forceinline__ float lo16(unsigned int v) { return __uint_as_float(v << 16); }
__device__ __forceinline__ float hi16(unsigned int v) { return __uint_as_float(v & 0xffff0000u); }

// ---------- template-named kernel (serves as cnt zeroing) ----------

__global__ __launch_bounds__(256) void GCNLarge_20761871909627_kernel(int* __restrict__ buf, int n) {
    int i = blockIdx.x * 256 + threadIdx.x;
    if (i < n) buf[i] = 0;
}

// ---------- runtime layout detection (wave-parallel) ----------
// flags[0]: edge_index int64 (1) vs int32 (0);  flags[1]: floats bf16 (1) vs f32 (0)

__global__ void detect_kernel(const int* __restrict__ ei, const unsigned int* __restrict__ xw,
                              int* __restrict__ flags) {
    int lane = threadIdx.x & 63;
    int any = 0;
    for (int k = lane; k < 128; k += 64) any |= ei[2 * k + 1];
    int hits = 0;
    for (int k = lane; k < 256; k += 64) {
        unsigned e = (xw[k] >> 7) & 0xFF;
        hits += (e >= 100 && e <= 140) ? 1 : 0;
    }
#pragma unroll
    for (int o = 32; o > 0; o >>= 1) {
        any |= __shfl_down(any, o);
        hits += __shfl_down(hits, o);
    }
    if (lane == 0) {
        flags[0] = (any == 0) ? 1 : 0;
        flags[1] = (hits >= 128) ? 1 : 0;
    }
}

__device__ __forceinline__ int edge_src(const int* ei, int e, int m) {
    return m ? ei[2 * (size_t)e] : ei[e];
}
__device__ __forceinline__ int edge_dst(const int* ei, int e, int m) {
    return m ? ei[2 * (size_t)NE + 2 * (size_t)e] : ei[(size_t)NE + e];
}

// ---------- degree / CSR build ----------

__global__ __launch_bounds__(256) void count_kernel(const int* __restrict__ ei,
                                                    const int* __restrict__ flags,
                                                    int* __restrict__ cnt) {
    int e = blockIdx.x * 256 + threadIdx.x;
    if (e < NE) {
        int d = edge_dst(ei, e, flags[0]);
        if ((unsigned)d < NN) atomicAdd(&cnt[d], 1);
    }
}

__global__ __launch_bounds__(256) void dis_kernel(const int* __restrict__ cnt,
                                                  float* __restrict__ dis) {
    int i = blockIdx.x * 256 + threadIdx.x;
    if (i < NNP) {
        int c = (i < NN) ? cnt[i] : 0;
        if (c < 0) c = 0;
        dis[i] = rsqrtf((float)(c + 1));
    }
}

__global__ __launch_bounds__(1024) void scan1_kernel(const int* __restrict__ cnt,
                                                     int* __restrict__ off,
                                                     int* __restrict__ bsum) {
    __shared__ int s[1024];
    int i = blockIdx.x * 1024 + threadIdx.x;
    int v = (i < NN) ? cnt[i] : 0;
    s[threadIdx.x] = v;
    __syncthreads();
    for (int d = 1; d < 1024; d <<= 1) {
        int tv = (threadIdx.x >= d) ? s[threadIdx.x - d] : 0;
        __syncthreads();
        s[threadIdx.x] += tv;
        __syncthreads();
    }
    if (i < NN) off[i] = s[threadIdx.x] - v;
    if (threadIdx.x == 1023) bsum[blockIdx.x] = s[1023];
}

__global__ void scan2_kernel(int* __restrict__ bsum, int nb) {
    if (threadIdx.x == 0 && blockIdx.x == 0) {
        int acc = 0;
        for (int b = 0; b < nb; b++) { int v = bsum[b]; bsum[b] = acc; acc += v; }
    }
}

__global__ __launch_bounds__(1024) void scan3_kernel(int* __restrict__ off,
                                                     const int* __restrict__ bsum,
                                                     int* __restrict__ cursor) {
    int i = blockIdx.x * 1024 + threadIdx.x;
    if (i < NN) { int o = off[i] + bsum[blockIdx.x]; off[i] = o; cursor[i] = o; }
    if (i == 0) off[NN] = NE;
}

__global__ __launch_bounds__(256) void place_kernel(const int* __restrict__ ei,
                                                    const int* __restrict__ flags,
                                                    int* __restrict__ cursor,
                                                    int* __restrict__ csr) {
    int e = blockIdx.x * 256 + threadIdx.x;
    if (e < NE) {
        int m = flags[0];
        int s = edge_src(ei, e, m);
        int d = edge_dst(ei, e, m);
        if ((unsigned)s < NN && (unsigned)d < NN) {
            int slot = atomicAdd(&cursor[d], 1);
            if ((unsigned)slot < NE) csr[slot] = s;
        }
    }
}

// ---------- W -> W^T (bf16) in global: Wt[n][k] = W[k][n], zero-padded to Kpad ----------

__global__ __launch_bounds__(256) void wt_kernel(const void* __restrict__ W,
                                                 const int* __restrict__ flags,
                                                 unsigned short* __restrict__ Wt,
                                                 int K, int Kpad, int total) {
    int idx = blockIdx.x * 256 + threadIdx.x;
    if (idx >= total) return;
    int n = idx / Kpad, k = idx - n * Kpad;
    unsigned short v = 0;
    if (k < K) {
        if (flags[1]) v = ((const unsigned short*)W)[(size_t)k * HID + n];
        else          v = f2bf(((const float*)W)[(size_t)k * HID + n]);
    }
    Wt[idx] = v;
}

// ---------- MFMA GEMM, layers 2-4: bf16 [NNP,128] @ (Wt bf16 [128][128]) -> bf16, row-scaled ----------

__global__ __launch_bounds__(256) void gemm128m_kernel(const unsigned short* __restrict__ A,
                                                       const unsigned short* __restrict__ Wt,
                                                       const float* __restrict__ dis,
                                                       unsigned short* __restrict__ out) {
    __shared__ unsigned short As[64 * LDK];
    __shared__ unsigned short Bs[128 * LDK];
    int tid = threadIdx.x;
    int r0 = blockIdx.x * 64;
    for (int idx = tid; idx < 1024; idx += 256) {      // A: 64 rows x 16 x (8 bf16)
        int r = idx >> 4, q = idx & 15;
        *(short8*)&As[r * LDK + q * 8] = *(const short8*)(A + (size_t)(r0 + r) * HID + q * 8);
    }
    for (int idx = tid; idx < 2048; idx += 256) {      // Wt: 128 rows x 16 x (8 bf16)
        int n = idx >> 4, q = idx & 15;
        *(short8*)&Bs[n * LDK + q * 8] = *(const short8*)(Wt + (size_t)n * HID + q * 8);
    }
    __syncthreads();
    int w = tid >> 6, lane = tid & 63;
    int m = lane & 15, quad = lane >> 4;
    int mbase = (w >> 1) * 32, nbase = (w & 1) * 64;
    f32x4 acc[2][4] = {};
#pragma unroll
    for (int kq = 0; kq < 4; kq++) {
        short8 a0 = *(const short8*)&As[(mbase + m) * LDK + kq * 32 + quad * 8];
        short8 a1 = *(const short8*)&As[(mbase + 16 + m) * LDK + kq * 32 + quad * 8];
#pragma unroll
        for (int nt = 0; nt < 4; nt++) {
            short8 b = *(const short8*)&Bs[(nbase + nt * 16 + m) * LDK + kq * 32 + quad * 8];
            acc[0][nt] = __builtin_amdgcn_mfma_f32_16x16x32_bf16(a0, b, acc[0][nt], 0, 0, 0);
            acc[1][nt] = __builtin_amdgcn_mfma_f32_16x16x32_bf16(a1, b, acc[1][nt], 0, 0, 0);
        }
    }
#pragma unroll
    for (int mt = 0; mt < 2; mt++) {
        int rb = r0 + mbase + mt * 16 + quad * 4;      // C/D: row = quad*4+reg, col = lane&15
#pragma unroll
        for (int reg = 0; reg < 4; reg++) {
            float d = dis[rb + reg];
#pragma unroll
            for (int nt = 0; nt < 4; nt++)
                out[(size_t)(rb + reg) * HID + nbase + nt * 16 + m] = f2bf(acc[mt][nt][reg] * d);
        }
    }
}

// ---------- MFMA GEMM, layer 1: x [NN,500] @ (Wt1 bf16 [128][512]) -> bf16, row-scaled ----------

__global__ __launch_bounds__(256) void gemm1m_kernel(const void* __restrict__ Av,
                                                     const unsigned short* __restrict__ Wt1,
                                                     const float* __restrict__ dis,
                                                     const int* __restrict__ flags,
                                                     unsigned short* __restrict__ out) {
    __shared__ unsigned short As[64 * LDK];
    __shared__ unsigned short Bs[128 * LDK];
    int tid = threadIdx.x;
    int r0 = blockIdx.x * 64;
    int bf = flags[1];
    int w = tid >> 6, lane = tid & 63;
    int m = lane & 15, quad = lane >> 4;
    int mbase = (w >> 1) * 32, nbase = (w & 1) * 64;
    f32x4 acc[2][4] = {};
    for (int kc = 0; kc < 4; kc++) {
        int k0 = kc * 128;
        __syncthreads();
        for (int idx = tid; idx < 2048; idx += 256) {  // A chunk: 64 rows x 32 x (4 bf16)
            int r = idx >> 5, q = idx & 31;
            int grow = r0 + r; if (grow >= NN) grow = NN - 1;
            int kk = k0 + q * 4;
            ushort4 val;
            if (kk + 4 <= FIN) {
                if (bf) val = *(const ushort4*)((const unsigned short*)Av + (size_t)grow * FIN + kk);
                else {
                    const float* fp = (const float*)Av + (size_t)grow * FIN + kk;
                    val = make_ushort4(f2bf(fp[0]), f2bf(fp[1]), f2bf(fp[2]), f2bf(fp[3]));
                }
            } else val = make_ushort4(0, 0, 0, 0);
            *(ushort4*)&As[r * LDK + q * 4] = val;
        }
        for (int idx = tid; idx < 2048; idx += 256) {  // Wt chunk: 128 rows x 16 x (8 bf16)
            int n = idx >> 4, q = idx & 15;
            *(short8*)&Bs[n * LDK + q * 8] = *(const short8*)(Wt1 + (size_t)n * 512 + k0 + q * 8);
        }
        __syncthreads();
#pragma unroll
        for (int kq = 0; kq < 4; kq++) {
            short8 a0 = *(const short8*)&As[(mbase + m) * LDK + kq * 32 + quad * 8];
            short8 a1 = *(const short8*)&As[(mbase + 16 + m) * LDK + kq * 32 + quad * 8];
#pragma unroll
            for (int nt = 0; nt < 4; nt++) {
                short8 b = *(const short8*)&Bs[(nbase + nt * 16 + m) * LDK + kq * 32 + quad * 8];
                acc[0][nt] = __builtin_amdgcn_mfma_f32_16x16x32_bf16(a0, b, acc[0][nt], 0, 0, 0);
                acc[1][nt] = __builtin_amdgcn_mfma_f32_16x16x32_bf16(a1, b, acc[1][nt], 0, 0, 0);
            }
        }
    }
#pragma unroll
    for (int mt = 0; mt < 2; mt++) {
        int rb = r0 + mbase + mt * 16 + quad * 4;
#pragma unroll
        for (int reg = 0; reg < 4; reg++) {
            int row = rb + reg;
            if (row < NN) {
                float d = dis[row];
#pragma unroll
                for (int nt = 0; nt < 4; nt++)
                    out[(size_t)row * HID + nbase + nt * 16 + m] = f2bf(acc[mt][nt][reg] * d);
            }
        }
    }
}

// ---------- aggregation over bf16 features, f32 accumulate, 4x unrolled for MLP ----------
// scale_src=0 (tin pre-scaled by dis[row]): out[i] = relu(dis[i]*(t[i] + sum t[src]) + b)
// scale_src=1 (tin unscaled):               out[i] = dis[i]*(dis[i]*t[i] + sum dis[src]*t[src])

__global__ __launch_bounds__(256) void aggb_kernel(const unsigned short* __restrict__ tin,
                                                   const int* __restrict__ off,
                                                   const int* __restrict__ csr,
                                                   const float* __restrict__ dis,
                                                   const void* __restrict__ bias,
                                                   const int* __restrict__ flags,
                                                   unsigned short* __restrict__ hout,
                                                   int relu, int scale_src) {
    int node = blockIdx.x * 4 + (threadIdx.x >> 6);   // one wave per node
    int lane = threadIdx.x & 63;                      // 2 features per lane (1 dword)
    float di = dis[node];
    unsigned int sv = *(const unsigned int*)(tin + (size_t)node * HID + lane * 2);
    float acc0 = scale_src ? di * lo16(sv) : lo16(sv);
    float acc1 = scale_src ? di * hi16(sv) : hi16(sv);
    int e0 = off[node], e1 = off[node + 1];
    if (e0 < 0) e0 = 0;
    if (e1 > NE) e1 = NE;
    int e = e0;
    if (!scale_src) {
        for (; e + 4 <= e1; e += 4) {
            // wave-uniform index loads (scalar), then 4 independent row loads in flight
            int i0 = csr[e], i1 = csr[e + 1], i2 = csr[e + 2], i3 = csr[e + 3];
            unsigned int v0 = *(const unsigned int*)(tin + (size_t)i0 * HID + lane * 2);
            unsigned int v1 = *(const unsigned int*)(tin + (size_t)i1 * HID + lane * 2);
            unsigned int v2 = *(const unsigned int*)(tin + (size_t)i2 * HID + lane * 2);
            unsigned int v3 = *(const unsigned int*)(tin + (size_t)i3 * HID + lane * 2);
            acc0 += lo16(v0); acc1 += hi16(v0);
            acc0 += lo16(v1); acc1 += hi16(v1);
            acc0 += lo16(v2); acc1 += hi16(v2);
            acc0 += lo16(v3); acc1 += hi16(v3);
        }
        for (; e < e1; e++) {
            int s = csr[e];
            unsigned int v = *(const unsigned int*)(tin + (size_t)s * HID + lane * 2);
            acc0 += lo16(v); acc1 += hi16(v);
        }
    } else {
        for (; e + 4 <= e1; e += 4) {
            int i0 = csr[e], i1 = csr[e + 1], i2 = csr[e + 2], i3 = csr[e + 3];
            unsigned int v0 = *(const unsigned int*)(tin + (size_t)i0 * HID + lane * 2);
            unsigned int v1 = *(const unsigned int*)(tin + (size_t)i1 * HID + lane * 2);
            unsigned int v2 = *(const unsigned int*)(tin + (size_t)i2 * HID + lane * 2);
            unsigned int v3 = *(const unsigned int*)(tin + (size_t)i3 * HID + lane * 2);
            float m0 = dis[i0], m1 = dis[i1], m2 = dis[i2], m3 = dis[i3];
            acc0 += m0 * lo16(v0); acc1 += m0 * hi16(v0);
            acc0 += m1 * lo16(v1); acc1 += m1 * hi16(v1);
            acc0 += m2 * lo16(v2); acc1 += m2 * hi16(v2);
            acc0 += m3 * lo16(v3); acc1 += m3 * hi16(v3);
        }
        for (; e < e1; e++) {
            int s = csr[e];
            unsigned int v = *(const unsigned int*)(tin + (size_t)s * HID + lane * 2);
            float mm = dis[s];
            acc0 += mm * lo16(v); acc1 += mm * hi16(v);
        }
    }
    float o0 = di * acc0, o1 = di * acc1;
    if (bias) {
        if (flags[1]) { o0 += bf2f(((const unsigned short*)bias)[lane * 2]);
                        o1 += bf2f(((const unsigned short*)bias)[lane * 2 + 1]); }
        else          { o0 += ((const float*)bias)[lane * 2];
                        o1 += ((const float*)bias)[lane * 2 + 1]; }
    }
    if (relu) { o0 = fmaxf(o0, 0.f); o1 = fmaxf(o1, 0.f); }
    unsigned int pk = ((unsigned int)f2bf(o1) << 16) | (unsigned int)f2bf(o0);
    *(unsigned int*)(hout + (size_t)node * HID + lane * 2) = pk;
}

// ---------- layer 5: bf16 [NN,128] @ W5 [128,3] + b5 -> out (dtype per flags[1]) ----------

__global__ __launch_bounds__(256) void gemm5_kernel(const unsigned short* __restrict__ A,
                                                    const void* __restrict__ W5v,
                                                    const void* __restrict__ b5v,
                                                    const int* __restrict__ flags,
                                                    void* __restrict__ outv) {
    __shared__ float Ws[384];
    __shared__ float bs[3];
    int tid = threadIdx.x;
    int bf = flags[1];
    for (int idx = tid; idx < 384; idx += 256)
        Ws[idx] = bf ? bf2f(((const unsigned short*)W5v)[idx]) : ((const float*)W5v)[idx];
    if (tid < 3)
        bs[tid] = bf ? bf2f(((const unsigned short*)b5v)[tid]) : ((const float*)b5v)[tid];
    __syncthreads();
    int lane = tid & 63;
    int row = blockIdx.x * 4 + (tid >> 6);
    float a0 = bf2f(A[(size_t)row * HID + lane]);
    float a1 = bf2f(A[(size_t)row * HID + 64 + lane]);
    float c0 = a0 * Ws[lane * 3 + 0] + a1 * Ws[(lane + 64) * 3 + 0];
    float c1 = a0 * Ws[lane * 3 + 1] + a1 * Ws[(lane + 64) * 3 + 1];
    float c2 = a0 * Ws[lane * 3 + 2] + a1 * Ws[(lane + 64) * 3 + 2];
#pragma unroll
    for (int o = 32; o > 0; o >>= 1) {
        c0 += __shfl_down(c0, o);
        c1 += __shfl_down(c1, o);
        c2 += __shfl_down(c2, o);
    }
    if (lane == 0) {
        c0 += bs[0]; c1 += bs[1]; c2 += bs[2];
        if (bf) {
            unsigned short* out = (unsigned short*)outv;
            out[(size_t)row * 3 + 0] = f2bf(c0);
            out[(size_t)row * 3 + 1] = f2bf(c1);
            out[(size_t)row * 3 + 2] = f2bf(c2);
        } else {
            float* out = (float*)outv;
            out[(size_t)row * 3 + 0] = c0;
            out[(size_t)row * 3 + 1] = c1;
            out[(size_t)row * 3 + 2] = c2;
        }
    }
}

extern "C" void kernel_launch(void* const* d_in, const int* in_sizes, int n_in,
                              void* d_out, int out_size, void* d_ws, size_t ws_size,
                              hipStream_t stream) {
    // Resolve inputs BY SIZE (ordering-robust).
    const void* x = nullptr; const int* ei = nullptr;
    const void* W1 = nullptr; const void* W5 = nullptr; const void* b5 = nullptr;
    const void* Wmid[3] = {nullptr, nullptr, nullptr};
    const void* bvec[4] = {nullptr, nullptr, nullptr, nullptr};
    int nw = 0, nb = 0;
    for (int i = 0; i < n_in; i++) {
        int s = in_sizes[i];
        if      (s == 50000000) x = d_in[i];
        else if (s == 3200000)  ei = (const int*)d_in[i];
        else if (s == 64000)    W1 = d_in[i];
        else if (s == 16384)  { if (nw < 3) Wmid[nw++] = d_in[i]; }
        else if (s == 384)      W5 = d_in[i];
        else if (s == 128)    { if (nb < 4) bvec[nb++] = d_in[i]; }
        else if (s == 3)        b5 = d_in[i];
    }
    if (!x || !ei || !W1 || !W5 || !b5 || nw < 3 || nb < 4) return;

    char* p = (char*)d_ws;
    auto alloc = [&](size_t bytes) { char* q = p; p += (bytes + 255) & ~(size_t)255; return (void*)q; };
    int*   flags = (int*)alloc(256);
    float* dis   = (float*)alloc((size_t)NNP * 4);
    int*   cnt   = (int*)alloc((size_t)NN * 4);
    int*   off   = (int*)alloc((size_t)(NN + 1) * 4);
    int*   cur   = (int*)alloc((size_t)NN * 4);
    int*   bsum  = (int*)alloc(128 * 4);
    int*   csr   = (int*)alloc((size_t)NE * 4);
    unsigned short* Wt1 = (unsigned short*)alloc((size_t)128 * 512 * 2);
    unsigned short* Wt2 = (unsigned short*)alloc((size_t)128 * 128 * 2);
    unsigned short* Wt3 = (unsigned short*)alloc((size_t)128 * 128 * 2);
    unsigned short* Wt4 = (unsigned short*)alloc((size_t)128 * 128 * 2);
    unsigned short* T   = (unsigned short*)alloc((size_t)NNP * HID * 2);
    unsigned short* H   = (unsigned short*)alloc((size_t)NNP * HID * 2);

    // graph build + weight transposes
    GCNLarge_20761871909627_kernel<<<(NN + 255) / 256, 256, 0, stream>>>(cnt, NN);
    detect_kernel<<<1, 64, 0, stream>>>(ei, (const unsigned int*)x, flags);
    wt_kernel<<<256, 256, 0, stream>>>(W1, flags, Wt1, FIN, 512, 128 * 512);
    wt_kernel<<<64, 256, 0, stream>>>(Wmid[0], flags, Wt2, HID, 128, 128 * 128);
    wt_kernel<<<64, 256, 0, stream>>>(Wmid[1], flags, Wt3, HID, 128, 128 * 128);
    wt_kernel<<<64, 256, 0, stream>>>(Wmid[2], flags, Wt4, HID, 128, 128 * 128);
    count_kernel<<<(NE + 255) / 256, 256, 0, stream>>>(ei, flags, cnt);
    dis_kernel<<<(NNP + 255) / 256, 256, 0, stream>>>(cnt, dis);
    scan1_kernel<<<98, 1024, 0, stream>>>(cnt, off, bsum);
    scan2_kernel<<<1, 64, 0, stream>>>(bsum, 98);
    scan3_kernel<<<98, 1024, 0, stream>>>(off, bsum, cur);
    place_kernel<<<(NE + 255) / 256, 256, 0, stream>>>(ei, flags, cur, csr);

    const int GB = NNP / 64;
    // layer 1
    gemm1m_kernel<<<GB, 256, 0, stream>>>(x, Wt1, dis, flags, T);
    aggb_kernel<<<NN / 4, 256, 0, stream>>>(T, off, csr, dis, bvec[0], flags, H, 1, 0);
    // layers 2-4 (T/H ping-pong)
    gemm128m_kernel<<<GB, 256, 0, stream>>>(H, Wt2, dis, T);
    aggb_kernel<<<NN / 4, 256, 0, stream>>>(T, off, csr, dis, bvec[1], flags, H, 1, 0);
    gemm128m_kernel<<<GB, 256, 0, stream>>>(H, Wt3, dis, T);
    aggb_kernel<<<NN / 4, 256, 0, stream>>>(T, off, csr, dis, bvec[2], flags, H, 1, 0);
    gemm128m_kernel<<<GB, 256, 0, stream>>>(H, Wt4, dis, T);
    aggb_kernel<<<NN / 4, 256, 0, stream>>>(T, off, csr, dis, bvec[3], flags, H, 1, 0);
    // layer 5: aggregate first (linearity), then small GEMM
    aggb_kernel<<<NN / 4, 256, 0, stream>>>(H, off, csr, dis, nullptr, flags, T, 0, 1);
    gemm5_kernel<<<NN / 4, 256, 0, stream>>>(T, W5, b5, flags, d_out);
}

// Round 7
// 1003.201 us; speedup vs baseline: 1.9110x; 1.0104x over previous
//
#include <hip/hip_runtime.h>
#include <hip/hip_bf16.h>

#define NN 100000
#define NNP 100096   // padded rows: multiple of 256
#define NE 1600000
#define FIN 500
#define HID 128

typedef __attribute__((ext_vector_type(8))) short short8;   // 8 bf16 = 4 VGPRs (MFMA A/B frag)
typedef __attribute__((ext_vector_type(4))) float f32x4;    // MFMA C/D frag

__device__ __forceinline__ float bf2f(unsigned short u) {
    return __uint_as_float(((unsigned int)u) << 16);
}
__device__ __forceinline__ unsigned short f2bf(float f) {
    __hip_bfloat16 h = __float2bfloat16(f);
    return *(unsigned short*)&h;
}
__device__ __forceinline__ float lo16(unsigned int v) { return __uint_as_float(v << 16); }
__device__ __forceinline__ float hi16(unsigned int v) { return __uint_as_float(v & 0xffff0000u); }

// ---------- template-named kernel (serves as cnt zeroing) ----------

__global__ __launch_bounds__(256) void GCNLarge_20761871909627_kernel(int* __restrict__ buf, int n) {
    int i = blockIdx.x * 256 + threadIdx.x;
    if (i < n) buf[i] = 0;
}

// ---------- runtime layout detection (wave-parallel) ----------

__global__ void detect_kernel(const int* __restrict__ ei, const unsigned int* __restrict__ xw,
                              int* __restrict__ flags) {
    int lane = threadIdx.x & 63;
    int any = 0;
    for (int k = lane; k < 128; k += 64) any |= ei[2 * k + 1];
    int hits = 0;
    for (int k = lane; k < 256; k += 64) {
        unsigned e = (xw[k] >> 7) & 0xFF;
        hits += (e >= 100 && e <= 140) ? 1 : 0;
    }
#pragma unroll
    for (int o = 32; o > 0; o >>= 1) {
        any |= __shfl_down(any, o);
        hits += __shfl_down(hits, o);
    }
    if (lane == 0) {
        flags[0] = (any == 0) ? 1 : 0;
        flags[1] = (hits >= 128) ? 1 : 0;
    }
}

__device__ __forceinline__ int edge_src(const int* ei, int e, int m) {
    return m ? ei[2 * (size_t)e] : ei[e];
}
__device__ __forceinline__ int edge_dst(const int* ei, int e, int m) {
    return m ? ei[2 * (size_t)NE + 2 * (size_t)e] : ei[(size_t)NE + e];
}

// ---------- degree / CSR build ----------

__global__ __launch_bounds__(256) void count_kernel(const int* __restrict__ ei,
                                                    const int* __restrict__ flags,
                                                    int* __restrict__ cnt) {
    int e = blockIdx.x * 256 + threadIdx.x;
    if (e < NE) {
        int d = edge_dst(ei, e, flags[0]);
        if ((unsigned)d < NN) atomicAdd(&cnt[d], 1);
    }
}

__global__ __launch_bounds__(256) void dis_kernel(const int* __restrict__ cnt,
                                                  float* __restrict__ dis) {
    int i = blockIdx.x * 256 + threadIdx.x;
    if (i < NNP) {
        int c = (i < NN) ? cnt[i] : 0;
        if (c < 0) c = 0;
        dis[i] = rsqrtf((float)(c + 1));
    }
}

__global__ __launch_bounds__(1024) void scan1_kernel(const int* __restrict__ cnt,
                                                     int* __restrict__ off,
                                                     int* __restrict__ bsum) {
    __shared__ int s[1024];
    int i = blockIdx.x * 1024 + threadIdx.x;
    int v = (i < NN) ? cnt[i] : 0;
    s[threadIdx.x] = v;
    __syncthreads();
    for (int d = 1; d < 1024; d <<= 1) {
        int tv = (threadIdx.x >= d) ? s[threadIdx.x - d] : 0;
        __syncthreads();
        s[threadIdx.x] += tv;
        __syncthreads();
    }
    if (i < NN) off[i] = s[threadIdx.x] - v;
    if (threadIdx.x == 1023) bsum[blockIdx.x] = s[1023];
}

__global__ void scan2_kernel(int* __restrict__ bsum, int nb) {
    if (threadIdx.x == 0 && blockIdx.x == 0) {
        int acc = 0;
        for (int b = 0; b < nb; b++) { int v = bsum[b]; bsum[b] = acc; acc += v; }
    }
}

__global__ __launch_bounds__(1024) void scan3_kernel(int* __restrict__ off,
                                                     const int* __restrict__ bsum,
                                                     int* __restrict__ cursor) {
    int i = blockIdx.x * 1024 + threadIdx.x;
    if (i < NN) { int o = off[i] + bsum[blockIdx.x]; off[i] = o; cursor[i] = o; }
    if (i == 0) off[NN] = NE;
}

__global__ __launch_bounds__(256) void place_kernel(const int* __restrict__ ei,
                                                    const int* __restrict__ flags,
                                                    int* __restrict__ cursor,
                                                    int* __restrict__ csr) {
    int e = blockIdx.x * 256 + threadIdx.x;
    if (e < NE) {
        int m = flags[0];
        int s = edge_src(ei, e, m);
        int d = edge_dst(ei, e, m);
        if ((unsigned)s < NN && (unsigned)d < NN) {
            int slot = atomicAdd(&cursor[d], 1);
            if ((unsigned)slot < NE) csr[slot] = s;
        }
    }
}

// ---------- W -> W^T (bf16) in global: Wt[n][k] = W[k][n], zero-padded to Kpad ----------

__global__ __launch_bounds__(256) void wt_kernel(const void* __restrict__ W,
                                                 const int* __restrict__ flags,
                                                 unsigned short* __restrict__ Wt,
                                                 int K, int Kpad, int total) {
    int idx = blockIdx.x * 256 + threadIdx.x;
    if (idx >= total) return;
    int n = idx / Kpad, k = idx - n * Kpad;
    unsigned short v = 0;
    if (k < K) {
        if (flags[1]) v = ((const unsigned short*)W)[(size_t)k * HID + n];
        else          v = f2bf(((const float*)W)[(size_t)k * HID + n]);
    }
    Wt[idx] = v;
}

// ---------- layers 2-4: barrier-free register GEMM ----------
// bf16 [NNP,128] @ Wt[128][128] -> bf16, row-scaled by dis. B frags in regs (loaded once
// per block), A frags direct from global (16 coalesced 64B lines per load instr), 4 row
// tiles per block with ping-pong A prefetch. No LDS, no __syncthreads.

__global__ __launch_bounds__(256) void gemmWr_kernel(const unsigned short* __restrict__ A,
                                                     const unsigned short* __restrict__ Wt,
                                                     const float* __restrict__ dis,
                                                     unsigned short* __restrict__ out) {
    int tid = threadIdx.x;
    int w = tid >> 6, lane = tid & 63;
    int m = lane & 15, quad = lane >> 4;
    int mbase = (w >> 1) * 32, nbase = (w & 1) * 64;
    short8 b[4][4];
#pragma unroll
    for (int nt = 0; nt < 4; nt++)
#pragma unroll
        for (int kq = 0; kq < 4; kq++)
            b[nt][kq] = *(const short8*)(Wt + (size_t)(nbase + nt * 16 + m) * HID + kq * 32 + quad * 8);
    int t0 = blockIdx.x * 4;
    short8 aP[4][2], aQ[4][2];
    auto loadA = [&](int t, short8 a[4][2]) {
        const unsigned short* p0 = A + (size_t)(t * 64 + mbase + m) * HID + quad * 8;
        const unsigned short* p1 = p0 + (size_t)16 * HID;
#pragma unroll
        for (int kq = 0; kq < 4; kq++) {
            a[kq][0] = *(const short8*)(p0 + kq * 32);
            a[kq][1] = *(const short8*)(p1 + kq * 32);
        }
    };
    loadA(t0, aP);
#pragma unroll
    for (int tt = 0; tt < 4; tt++) {
        if (tt < 3) loadA(t0 + tt + 1, (tt & 1) ? aP : aQ);
        short8 (*ac)[2] = (tt & 1) ? aQ : aP;
        f32x4 acc[2][4] = {};
#pragma unroll
        for (int kq = 0; kq < 4; kq++)
#pragma unroll
            for (int nt = 0; nt < 4; nt++) {
                acc[0][nt] = __builtin_amdgcn_mfma_f32_16x16x32_bf16(ac[kq][0], b[nt][kq], acc[0][nt], 0, 0, 0);
                acc[1][nt] = __builtin_amdgcn_mfma_f32_16x16x32_bf16(ac[kq][1], b[nt][kq], acc[1][nt], 0, 0, 0);
            }
        int r0 = (t0 + tt) * 64;
#pragma unroll
        for (int mt = 0; mt < 2; mt++) {
            int rb = r0 + mbase + mt * 16 + quad * 4;
#pragma unroll
            for (int reg = 0; reg < 4; reg++) {
                float d = dis[rb + reg];
#pragma unroll
                for (int nt = 0; nt < 4; nt++)
                    out[(size_t)(rb + reg) * HID + nbase + nt * 16 + m] = f2bf(acc[mt][nt][reg] * d);
            }
        }
    }
}

// ---------- layer 1: barrier-free register GEMM, x [NN,500] @ Wt1[128][512] ----------

__global__ __launch_bounds__(256) void gemm1r_kernel(const void* __restrict__ Av,
                                                     const unsigned short* __restrict__ Wt1,
                                                     const float* __restrict__ dis,
                                                     const int* __restrict__ flags,
                                                     unsigned short* __restrict__ out) {
    int tid = threadIdx.x;
    int bf = flags[1];
    int w = tid >> 6, lane = tid & 63;
    int m = lane & 15, quad = lane >> 4;
    int mbase = (w >> 1) * 32, nbase = (w & 1) * 64;
    int r0 = blockIdx.x * 64;
    int row0 = r0 + mbase + m;       int rc0 = (row0 < NN) ? row0 : NN - 1;
    int row1 = r0 + mbase + 16 + m;  int rc1 = (row1 < NN) ? row1 : NN - 1;
    f32x4 acc[2][4] = {};
#pragma unroll
    for (int kc = 0; kc < 4; kc++) {
        short8 b[4][4];
#pragma unroll
        for (int nt = 0; nt < 4; nt++)
#pragma unroll
            for (int kq = 0; kq < 4; kq++)
                b[nt][kq] = *(const short8*)(Wt1 + (size_t)(nbase + nt * 16 + m) * 512 + kc * 128 + kq * 32 + quad * 8);
        short8 a[4][2];
#pragma unroll
        for (int kq = 0; kq < 4; kq++) {
            int k_off = kc * 128 + kq * 32 + quad * 8;
            ushort4 z = make_ushort4(0, 0, 0, 0);
#pragma unroll
            for (int mt = 0; mt < 2; mt++) {
                int rr = mt ? rc1 : rc0;
                ushort4 lo = z, hi = z;
                if (bf) {
                    const unsigned short* xp = (const unsigned short*)Av + (size_t)rr * FIN + k_off;
                    if (k_off + 4 <= FIN) lo = *(const ushort4*)xp;
                    if (k_off + 8 <= FIN) hi = *(const ushort4*)(xp + 4);
                } else {
                    const float* xp = (const float*)Av + (size_t)rr * FIN + k_off;
                    if (k_off + 4 <= FIN) { float4 f = *(const float4*)xp;
                        lo = make_ushort4(f2bf(f.x), f2bf(f.y), f2bf(f.z), f2bf(f.w)); }
                    if (k_off + 8 <= FIN) { float4 f = *(const float4*)(xp + 4);
                        hi = make_ushort4(f2bf(f.x), f2bf(f.y), f2bf(f.z), f2bf(f.w)); }
                }
                a[kq][mt] = short8{(short)lo.x, (short)lo.y, (short)lo.z, (short)lo.w,
                                   (short)hi.x, (short)hi.y, (short)hi.z, (short)hi.w};
            }
        }
#pragma unroll
        for (int kq = 0; kq < 4; kq++)
#pragma unroll
            for (int nt = 0; nt < 4; nt++) {
                acc[0][nt] = __builtin_amdgcn_mfma_f32_16x16x32_bf16(a[kq][0], b[nt][kq], acc[0][nt], 0, 0, 0);
                acc[1][nt] = __builtin_amdgcn_mfma_f32_16x16x32_bf16(a[kq][1], b[nt][kq], acc[1][nt], 0, 0, 0);
            }
    }
#pragma unroll
    for (int mt = 0; mt < 2; mt++) {
        int rb = r0 + mbase + mt * 16 + quad * 4;
#pragma unroll
        for (int reg = 0; reg < 4; reg++) {
            int row = rb + reg;
            if (row < NN) {
                float d = dis[row];
#pragma unroll
                for (int nt = 0; nt < 4; nt++)
                    out[(size_t)row * HID + nbase + nt * 16 + m] = f2bf(acc[mt][nt][reg] * d);
            }
        }
    }
}

// ---------- aggregation over bf16 features, f32 accumulate, 8x unrolled ----------

__global__ __launch_bounds__(256) void aggb_kernel(const unsigned short* __restrict__ tin,
                                                   const int* __restrict__ off,
                                                   const int* __restrict__ csr,
                                                   const float* __restrict__ dis,
                                                   const void* __restrict__ bias,
                                                   const int* __restrict__ flags,
                                                   unsigned short* __restrict__ hout,
                                                   int relu, int scale_src) {
    int node = blockIdx.x * 4 + (threadIdx.x >> 6);   // one wave per node
    int lane = threadIdx.x & 63;                      // 2 features per lane (1 dword)
    float di = dis[node];
    unsigned int sv = *(const unsigned int*)(tin + (size_t)node * HID + lane * 2);
    float acc0 = scale_src ? di * lo16(sv) : lo16(sv);
    float acc1 = scale_src ? di * hi16(sv) : hi16(sv);
    int e0 = off[node], e1 = off[node + 1];
    if (e0 < 0) e0 = 0;
    if (e1 > NE) e1 = NE;
    int e = e0;
    if (!scale_src) {
        for (; e + 8 <= e1; e += 8) {
            int i0 = csr[e],     i1 = csr[e + 1], i2 = csr[e + 2], i3 = csr[e + 3];
            int i4 = csr[e + 4], i5 = csr[e + 5], i6 = csr[e + 6], i7 = csr[e + 7];
            unsigned int v0 = *(const unsigned int*)(tin + (size_t)i0 * HID + lane * 2);
            unsigned int v1 = *(const unsigned int*)(tin + (size_t)i1 * HID + lane * 2);
            unsigned int v2 = *(const unsigned int*)(tin + (size_t)i2 * HID + lane * 2);
            unsigned int v3 = *(const unsigned int*)(tin + (size_t)i3 * HID + lane * 2);
            unsigned int v4 = *(const unsigned int*)(tin + (size_t)i4 * HID + lane * 2);
            unsigned int v5 = *(const unsigned int*)(tin + (size_t)i5 * HID + lane * 2);
            unsigned int v6 = *(const unsigned int*)(tin + (size_t)i6 * HID + lane * 2);
            unsigned int v7 = *(const unsigned int*)(tin + (size_t)i7 * HID + lane * 2);
            acc0 += lo16(v0); acc1 += hi16(v0); acc0 += lo16(v1); acc1 += hi16(v1);
            acc0 += lo16(v2); acc1 += hi16(v2); acc0 += lo16(v3); acc1 += hi16(v3);
            acc0 += lo16(v4); acc1 += hi16(v4); acc0 += lo16(v5); acc1 += hi16(v5);
            acc0 += lo16(v6); acc1 += hi16(v6); acc0 += lo16(v7); acc1 += hi16(v7);
        }
        for (; e + 4 <= e1; e += 4) {
            int i0 = csr[e], i1 = csr[e + 1], i2 = csr[e + 2], i3 = csr[e + 3];
            unsigned int v0 = *(const unsigned int*)(tin + (size_t)i0 * HID + lane * 2);
            unsigned int v1 = *(const unsigned int*)(tin + (size_t)i1 * HID + lane * 2);
            unsigned int v2 = *(const unsigned int*)(tin + (size_t)i2 * HID + lane * 2);
            unsigned int v3 = *(const unsigned int*)(tin + (size_t)i3 * HID + lane * 2);
            acc0 += lo16(v0); acc1 += hi16(v0); acc0 += lo16(v1); acc1 += hi16(v1);
            acc0 += lo16(v2); acc1 += hi16(v2); acc0 += lo16(v3); acc1 += hi16(v3);
        }
        for (; e < e1; e++) {
            int s = csr[e];
            unsigned int v = *(const unsigned int*)(tin + (size_t)s * HID + lane * 2);
            acc0 += lo16(v); acc1 += hi16(v);
        }
    } else {
        for (; e + 8 <= e1; e += 8) {
            int i0 = csr[e],     i1 = csr[e + 1], i2 = csr[e + 2], i3 = csr[e + 3];
            int i4 = csr[e + 4], i5 = csr[e + 5], i6 = csr[e + 6], i7 = csr[e + 7];
            unsigned int v0 = *(const unsigned int*)(tin + (size_t)i0 * HID + lane * 2);
            unsigned int v1 = *(const unsigned int*)(tin + (size_t)i1 * HID + lane * 2);
            unsigned int v2 = *(const unsigned int*)(tin + (size_t)i2 * HID + lane * 2);
            unsigned int v3 = *(const unsigned int*)(tin + (size_t)i3 * HID + lane * 2);
            unsigned int v4 = *(const unsigned int*)(tin + (size_t)i4 * HID + lane * 2);
            unsigned int v5 = *(const unsigned int*)(tin + (size_t)i5 * HID + lane * 2);
            unsigned int v6 = *(const unsigned int*)(tin + (size_t)i6 * HID + lane * 2);
            unsigned int v7 = *(const unsigned int*)(tin + (size_t)i7 * HID + lane * 2);
            float m0 = dis[i0], m1 = dis[i1], m2 = dis[i2], m3 = dis[i3];
            float m4 = dis[i4], m5 = dis[i5], m6 = dis[i6], m7 = dis[i7];
            acc0 += m0 * lo16(v0); acc1 += m0 * hi16(v0);
            acc0 += m1 * lo16(v1); acc1 += m1 * hi16(v1);
            acc0 += m2 * lo16(v2); acc1 += m2 * hi16(v2);
            acc0 += m3 * lo16(v3); acc1 += m3 * hi16(v3);
            acc0 += m4 * lo16(v4); acc1 += m4 * hi16(v4);
            acc0 += m5 * lo16(v5); acc1 += m5 * hi16(v5);
            acc0 += m6 * lo16(v6); acc1 += m6 * hi16(v6);
            acc0 += m7 * lo16(v7); acc1 += m7 * hi16(v7);
        }
        for (; e < e1; e++) {
            int s = csr[e];
            unsigned int v = *(const unsigned int*)(tin + (size_t)s * HID + lane * 2);
            float mm = dis[s];
            acc0 += mm * lo16(v); acc1 += mm * hi16(v);
        }
    }
    float o0 = di * acc0, o1 = di * acc1;
    if (bias) {
        if (flags[1]) { o0 += bf2f(((const unsigned short*)bias)[lane * 2]);
                        o1 += bf2f(((const unsigned short*)bias)[lane * 2 + 1]); }
        else          { o0 += ((const float*)bias)[lane * 2];
                        o1 += ((const float*)bias)[lane * 2 + 1]; }
    }
    if (relu) { o0 = fmaxf(o0, 0.f); o1 = fmaxf(o1, 0.f); }
    unsigned int pk = ((unsigned int)f2bf(o1) << 16) | (unsigned int)f2bf(o0);
    *(unsigned int*)(hout + (size_t)node * HID + lane * 2) = pk;
}

// ---------- layer 5: bf16 [NN,128] @ W5 [128,3] + b5 -> out (dtype per flags[1]) ----------

__global__ __launch_bounds__(256) void gemm5_kernel(const unsigned short* __restrict__ A,
                                                    const void* __restrict__ W5v,
                                                    const void* __restrict__ b5v,
                                                    const int* __restrict__ flags,
                                                    void* __restrict__ outv) {
    __shared__ float Ws[384];
    __shared__ float bs[3];
    int tid = threadIdx.x;
    int bf = flags[1];
    for (int idx = tid; idx < 384; idx += 256)
        Ws[idx] = bf ? bf2f(((const unsigned short*)W5v)[idx]) : ((const float*)W5v)[idx];
    if (tid < 3)
        bs[tid] = bf ? bf2f(((const unsigned short*)b5v)[tid]) : ((const float*)b5v)[tid];
    __syncthreads();
    int lane = tid & 63;
    int row = blockIdx.x * 4 + (tid >> 6);
    float a0 = bf2f(A[(size_t)row * HID + lane]);
    float a1 = bf2f(A[(size_t)row * HID + 64 + lane]);
    float c0 = a0 * Ws[lane * 3 + 0] + a1 * Ws[(lane + 64) * 3 + 0];
    float c1 = a0 * Ws[lane * 3 + 1] + a1 * Ws[(lane + 64) * 3 + 1];
    float c2 = a0 * Ws[lane * 3 + 2] + a1 * Ws[(lane + 64) * 3 + 2];
#pragma unroll
    for (int o = 32; o > 0; o >>= 1) {
        c0 += __shfl_down(c0, o);
        c1 += __shfl_down(c1, o);
        c2 += __shfl_down(c2, o);
    }
    if (lane == 0) {
        c0 += bs[0]; c1 += bs[1]; c2 += bs[2];
        if (bf) {
            unsigned short* out = (unsigned short*)outv;
            out[(size_t)row * 3 + 0] = f2bf(c0);
            out[(size_t)row * 3 + 1] = f2bf(c1);
            out[(size_t)row * 3 + 2] = f2bf(c2);
        } else {
            float* out = (float*)outv;
            out[(size_t)row * 3 + 0] = c0;
            out[(size_t)row * 3 + 1] = c1;
            out[(size_t)row * 3 + 2] = c2;
        }
    }
}

extern "C" void kernel_launch(void* const* d_in, const int* in_sizes, int n_in,
                              void* d_out, int out_size, void* d_ws, size_t ws_size,
                              hipStream_t stream) {
    const void* x = nullptr; const int* ei = nullptr;
    const void* W1 = nullptr; const void* W5 = nullptr; const void* b5 = nullptr;
    const void* Wmid[3] = {nullptr, nullptr, nullptr};
    const void* bvec[4] = {nullptr, nullptr, nullptr, nullptr};
    int nw = 0, nb = 0;
    for (int i = 0; i < n_in; i++) {
        int s = in_sizes[i];
        if      (s == 50000000) x = d_in[i];
        else if (s == 3200000)  ei = (const int*)d_in[i];
        else if (s == 64000)    W1 = d_in[i];
        else if (s == 16384)  { if (nw < 3) Wmid[nw++] = d_in[i]; }
        else if (s == 384)      W5 = d_in[i];
        else if (s == 128)    { if (nb < 4) bvec[nb++] = d_in[i]; }
        else if (s == 3)        b5 = d_in[i];
    }
    if (!x || !ei || !W1 || !W5 || !b5 || nw < 3 || nb < 4) return;

    char* p = (char*)d_ws;
    auto alloc = [&](size_t bytes) { char* q = p; p += (bytes + 255) & ~(size_t)255; return (void*)q; };
    int*   flags = (int*)alloc(256);
    float* dis   = (float*)alloc((size_t)NNP * 4);
    int*   cnt   = (int*)alloc((size_t)NN * 4);
    int*   off   = (int*)alloc((size_t)(NN + 1) * 4);
    int*   cur   = (int*)alloc((size_t)NN * 4);
    int*   bsum  = (int*)alloc(128 * 4);
    int*   csr   = (int*)alloc((size_t)NE * 4);
    unsigned short* Wt1 = (unsigned short*)alloc((size_t)128 * 512 * 2);
    unsigned short* Wt2 = (unsigned short*)alloc((size_t)128 * 128 * 2);
    unsigned short* Wt3 = (unsigned short*)alloc((size_t)128 * 128 * 2);
    unsigned short* Wt4 = (unsigned short*)alloc((size_t)128 * 128 * 2);
    unsigned short* T   = (unsigned short*)alloc((size_t)NNP * HID * 2);
    unsigned short* H   = (unsigned short*)alloc((size_t)NNP * HID * 2);

    // graph build + weight transposes
    GCNLarge_20761871909627_kernel<<<(NN + 255) / 256, 256, 0, stream>>>(cnt, NN);
    detect_kernel<<<1, 64, 0, stream>>>(ei, (const unsigned int*)x, flags);
    wt_kernel<<<256, 256, 0, stream>>>(W1, flags, Wt1, FIN, 512, 128 * 512);
    wt_kernel<<<64, 256, 0, stream>>>(Wmid[0], flags, Wt2, HID, 128, 128 * 128);
    wt_kernel<<<64, 256, 0, stream>>>(Wmid[1], flags, Wt3, HID, 128, 128 * 128);
    wt_kernel<<<64, 256, 0, stream>>>(Wmid[2], flags, Wt4, HID, 128, 128 * 128);
    count_kernel<<<(NE + 255) / 256, 256, 0, stream>>>(ei, flags, cnt);
    dis_kernel<<<(NNP + 255) / 256, 256, 0, stream>>>(cnt, dis);
    scan1_kernel<<<98, 1024, 0, stream>>>(cnt, off, bsum);
    scan2_kernel<<<1, 64, 0, stream>>>(bsum, 98);
    scan3_kernel<<<98, 1024, 0, stream>>>(off, bsum, cur);
    place_kernel<<<(NE + 255) / 256, 256, 0, stream>>>(ei, flags, cur, csr);

    // layer 1
    gemm1r_kernel<<<NNP / 64, 256, 0, stream>>>(x, Wt1, dis, flags, T);
    aggb_kernel<<<NN / 4, 256, 0, stream>>>(T, off, csr, dis, bvec[0], flags, H, 1, 0);
    // layers 2-4 (T/H ping-pong), 391 blocks x 4 tiles x 64 rows = NNP
    gemmWr_kernel<<<NNP / 256, 256, 0, stream>>>(H, Wt2, dis, T);
    aggb_kernel<<<NN / 4, 256, 0, stream>>>(T, off, csr, dis, bvec[1], flags, H, 1, 0);
    gemmWr_kernel<<<NNP / 256, 256, 0, stream>>>(H, Wt3, dis, T);
    aggb_kernel<<<NN / 4, 256, 0, stream>>>(T, off, csr, dis, bvec[2], flags, H, 1, 0);
    gemmWr_kernel<<<NNP / 256, 256, 0, stream>>>(H, Wt4, dis, T);
    aggb_kernel<<<NN / 4, 256, 0, stream>>>(T, off, csr, dis, bvec[3], flags, H, 1, 0);
    // layer 5: aggregate first (linearity), then small GEMM
    aggb_kernel<<<NN / 4, 256, 0, stream>>>(H, off, csr, dis, nullptr, flags, T, 0, 1);
    gemm5_kernel<<<NN / 4, 256, 0, stream>>>(T, W5, b5, flags, d_out);
}